// Round 4
// baseline (141.476 us; speedup 1.0000x reference)
//
#include <hip/hip_runtime.h>

namespace {
constexpr int CH = 128, HH = 56, WW = 56;
constexpr int R  = 2;    // h rows per block
constexpr int LP = 60;   // padded l-dim: [2 zeros][56][2 zeros]

__global__ __launch_bounds__(256, 4) void fused_conv_kernel(
    const float* __restrict__ x,
    const float* __restrict__ w0,
    const float* __restrict__ w1,
    float* __restrict__ out)
{
    __shared__ float t4s[R][2][4][LP];   // [r][m][i][lpad]
    __shared__ float w0s[2 * 3 * 3 * 32];

    const int tid = threadIdx.x;
    const int b   = blockIdx.x / (HH / R);
    const int hg  = blockIdx.x - b * (HH / R);
    const int h0  = hg * R;

    // stage w0 (tiny)
    for (int t = tid; t < 576; t += 256) w0s[t] = w0[t];

    // zero ONLY the pad columns (padded idx 0,1,58,59); disjoint from stage-1
    // writes (which cover padded idx 2..57)
    if (tid < R * 32) {
        int e = tid;
        const int r = e >> 5; e &= 31;
        const int m = e >> 4; e &= 15;
        const int i = e >> 2;
        const int p = e & 3;
        t4s[r][m][i][(p < 2) ? p : (56 + p)] = 0.f;
    }

    // ---- stage 1: channel mix, j-split across quads for MLP ----
    // tid = js + 4*(lq + 14*(m + 2*r));  js owns j = js*16 .. js*16+15.
    // Each thread loads 16 independent float4 (1KB/wave-instr, all in flight),
    // quad-allreduce via __shfl_xor, lane js writes the i=js row.
    if (tid < 224) {
        int e = tid;
        const int js = e & 3;  e >>= 2;
        const int lq = e % 14; e /= 14;
        const int m  = e & 1;
        const int r  = e >> 1;

        const float* xp = x + (((size_t)b * CH + 2 * (js * 16) + m) * HH + (h0 + r)) * WW + lq * 4;
        const size_t cstride = (size_t)2 * HH * WW;   // j -> j+1 is 2 channels

        float4 xv[16];
        #pragma unroll
        for (int jj = 0; jj < 16; ++jj)
            xv[jj] = *reinterpret_cast<const float4*>(xp + (size_t)jj * cstride);

        float4 acc[4] = {};   // acc[i] over the 4 l-values
        const float4* w1v = (const float4*)w1;
        #pragma unroll
        for (int jj = 0; jj < 16; ++jj) {
            const float4 wv = w1v[js * 16 + jj];
            #pragma unroll
            for (int i = 0; i < 4; ++i) {
                const float wvi = (i == 0) ? wv.x : (i == 1) ? wv.y : (i == 2) ? wv.z : wv.w;
                acc[i].x = fmaf(xv[jj].x, wvi, acc[i].x);
                acc[i].y = fmaf(xv[jj].y, wvi, acc[i].y);
                acc[i].z = fmaf(xv[jj].z, wvi, acc[i].z);
                acc[i].w = fmaf(xv[jj].w, wvi, acc[i].w);
            }
        }

        // quad allreduce over js (lanes differ in bits 0-1)
        #pragma unroll
        for (int i = 0; i < 4; ++i) {
            acc[i].x += __shfl_xor(acc[i].x, 1); acc[i].x += __shfl_xor(acc[i].x, 2);
            acc[i].y += __shfl_xor(acc[i].y, 1); acc[i].y += __shfl_xor(acc[i].y, 2);
            acc[i].z += __shfl_xor(acc[i].z, 1); acc[i].z += __shfl_xor(acc[i].z, 2);
            acc[i].w += __shfl_xor(acc[i].w, 1); acc[i].w += __shfl_xor(acc[i].w, 2);
        }

        const float4 my = (js == 0) ? acc[0] : (js == 1) ? acc[1] : (js == 2) ? acc[2] : acc[3];
        // padded idx 2+4lq is 8B-aligned: two float2 writes
        *reinterpret_cast<float2*>(&t4s[r][m][js][2 + 4 * lq])     = make_float2(my.x, my.y);
        *reinterpret_cast<float2*>(&t4s[r][m][js][2 + 4 * lq + 2]) = make_float2(my.z, my.w);
    }
    __syncthreads();

    // ---- stage 2: 9-tap conv along l + boundary fixups; 4 w per item ----
    #pragma unroll 2
    for (int it = 0; it < R * 7; ++it) {
        const int t  = it * 256 + tid;
        const int r  = t / 1792;
        const int tt = t - r * 1792;
        const int c  = tt / 14;          // output channel = j*4+i
        const int q  = tt - c * 14;
        const int l0 = q * 4;
        const int j  = c >> 2;
        const int i  = c & 3;

        const float* tp0 = &t4s[r][0][i][l0];
        const float* tp1 = &t4s[r][1][i][l0];
        const float4 p0a = *(const float4*)(tp0);
        const float4 p0b = *(const float4*)(tp0 + 4);
        const float4 p1a = *(const float4*)(tp1);
        const float4 p1b = *(const float4*)(tp1 + 4);
        const float v0[8] = {p0a.x, p0a.y, p0a.z, p0a.w, p0b.x, p0b.y, p0b.z, p0b.w};
        const float v1[8] = {p1a.x, p1a.y, p1a.z, p1a.w, p1b.x, p1b.y, p1b.z, p1b.w};

        float acc0 = 0.f, acc1 = 0.f, acc2 = 0.f, acc3 = 0.f;
        #pragma unroll
        for (int m = 0; m < 2; ++m) {
            #pragma unroll
            for (int kB = 0; kB < 3; ++kB) {
                #pragma unroll
                for (int kA = 0; kA < 3; ++kA) {
                    const float wv = w0s[((m * 3 + kB) * 3 + kA) * 32 + j];
                    const int dd = kA + kB;
                    acc0 = fmaf(m ? v1[dd]     : v0[dd],     wv, acc0);
                    acc1 = fmaf(m ? v1[dd + 1] : v0[dd + 1], wv, acc1);
                    acc2 = fmaf(m ? v1[dd + 2] : v0[dd + 2], wv, acc2);
                    acc3 = fmaf(m ? v1[dd + 3] : v0[dd + 3], wv, acc3);
                }
            }
        }

        // boundary fixups: kB=0 invalid at w=0; kB=2 invalid at w=55
        if (l0 == 0) {
            #pragma unroll
            for (int m = 0; m < 2; ++m)
                acc0 -= t4s[r][m][i][2] * w0s[((m * 3 + 0) * 3 + 2) * 32 + j];
        }
        if (l0 == 52) {
            #pragma unroll
            for (int m = 0; m < 2; ++m)
                acc3 -= t4s[r][m][i][57] * w0s[((m * 3 + 2) * 3 + 0) * 32 + j];
        }

        const int h_out = (h0 + r + 1) % HH;    // roll(+1) along H
        float* orow = out + (((size_t)b * CH + c) * HH + h_out) * WW + l0;
        *(float4*)orow = make_float4(acc0, acc1, acc2, acc3);
    }
}
} // namespace

extern "C" void kernel_launch(void* const* d_in, const int* in_sizes, int n_in,
                              void* d_out, int out_size, void* d_ws, size_t ws_size,
                              hipStream_t stream) {
    const float* x  = (const float*)d_in[0];
    const float* w0 = (const float*)d_in[1];
    const float* w1 = (const float*)d_in[2];
    float* out = (float*)d_out;
    fused_conv_kernel<<<dim3(128 * (HH / R)), dim3(256), 0, stream>>>(x, w0, w1, out);
}